// Round 4
// baseline (8293.594 us; speedup 1.0000x reference)
//
#include <hip/hip_runtime.h>
#include <hip/hip_bf16.h>

// ---------------- problem constants ----------------
#define UNITS    2000
#define FDIM     256
#define TSTEPS   1024
#define BATCH    64
#define KPAD     2304                 // 2000 h + 256 u + 48 pad = 32*72
#define NPAD     2048
#define WLSTR    2312                 // LDS W row stride (ushorts)
#define MT_STRIDE 73728               // ushorts per mtile = 72 ki * 1024
#define ABUF_USH 294912               // 4 mtiles * MT_STRIDE (per buffer)
#define WELEMS   ((size_t)NPAD * KPAD)
#define NBLK     250                  // 125 col-groups * 2 batch halves
#define REDOFF   (2*16*WLSTR)         // ushort offset of reduction scratch
#define SMEM_BYTES (REDOFF*2 + 8192)  // 147,968 + 8,192 = 156,160 B

typedef __attribute__((ext_vector_type(8))) short short8;   // 8 bf16
typedef __attribute__((ext_vector_type(4))) float f32x4;

static __device__ __forceinline__ ushort f2bf(float x) {
  union { float f; unsigned u; } v; v.f = x;
  unsigned r = v.u + 0x7fff + ((v.u >> 16) & 1);
  return (ushort)(r >> 16);
}
static __device__ __forceinline__ float bf2f(ushort h) {
  union { float f; unsigned u; } v; v.u = ((unsigned)h) << 16;
  return v.f;
}

// Cached 16-B load (L1+L2; per-step acquire fence handles cross-XCD coherence).
template<int OFF>
static __device__ __forceinline__ short8 load_cached(unsigned voff, const ushort* base) {
  short8 r;
  asm volatile("global_load_dwordx4 %0, %1, %2 offset:%3"
               : "=v"(r) : "v"(voff), "s"(base), "n"(OFF));
  return r;
}
// Write-through 2-B store (bypasses L1/L2, lands at the L3 coherence point).
template<int OFF>
static __device__ __forceinline__ void store_coh(unsigned voff, ushort* base, ushort val) {
  const unsigned v32 = val;
  asm volatile("global_store_short %0, %1, %2 offset:%3 sc0 sc1"
               :: "v"(voff), "v"(v32), "s"(base), "n"(OFF) : "memory");
}

// ---------------- W prep: transpose + bf16 hi/lo split (validated r1-r3) ----
__global__ void prep_w(const float* __restrict__ W_in, const float* __restrict__ W_res,
                       ushort* __restrict__ Wth, ushort* __restrict__ Wtl) {
  __shared__ float tile[32][33];
  const int tk = blockIdx.x, tn = blockIdx.y;
  const int tx = threadIdx.x, ty = threadIdx.y;
  const int n = tn * 32 + tx;
  #pragma unroll
  for (int i = 0; i < 32; i += 8) {
    const int k = tk * 32 + ty + i;
    float v = 0.f;
    if (n < UNITS) {
      if (k < UNITS)            v = W_res[(size_t)k * UNITS + n];
      else if (k < UNITS+FDIM)  v = W_in[(size_t)(k - UNITS) * UNITS + n];
    }
    tile[ty + i][tx] = v;
  }
  __syncthreads();
  #pragma unroll
  for (int i = 0; i < 32; i += 8) {
    const int row = tn * 32 + ty + i;
    const int kk  = tk * 32 + tx;
    const float v = tile[tx][ty + i];
    const ushort hi = f2bf(v);
    const ushort lo = f2bf(v - bf2f(hi));
    Wth[(size_t)row * KPAD + kk] = hi;
    Wtl[(size_t)row * KPAD + kk] = lo;
  }
}

// ---------------- A-buffer (fragment layout) + barrier init ----------------
// ushort offset F(row,k,part) = (row>>4)*MT_STRIDE + (k>>5)*1024 + part*512
//                              + ((k>>3)&3)*128 + (row&15)*8 + (k&7)
__global__ void init_abuf(const float* __restrict__ inp,
                          ushort* __restrict__ a0, ushort* __restrict__ a1,
                          unsigned* __restrict__ bar) {
  const int i = blockIdx.x * 256 + threadIdx.x;
  if (i < 2048) bar[i] = 0u;
  if (i >= ABUF_USH) return;
  const int mtile = i / MT_STRIDE;
  const int r1 = i - mtile * MT_STRIDE;
  const int ki  = r1 >> 10;
  const int rem = r1 & 1023;
  const int part = rem >> 9;
  const int lk  = (rem >> 7) & 3;
  const int l15 = (rem >> 3) & 15;
  const int el  = rem & 7;
  const int row = mtile * 16 + l15;
  const int k   = ki * 32 + lk * 8 + el;
  ushort v = 0;
  if (k >= UNITS && k < UNITS + FDIM) {
    const float u = inp[(size_t)row * TSTEPS * FDIM + (k - UNITS)];   // t = 0
    const ushort hi = f2bf(u);
    v = part ? f2bf(u - bf2f(hi)) : hi;
  }
  a0[i] = v; a1[i] = 0;
}

// ---------------- the scan ----------------
// 250 blocks x 512 thr (8 waves), 1 block/CU. Block (pb,cb): rows [pb*32,+32),
// cols [cb*16,+16). Wave ks owns K-eighth x both 16-row M-tiles (bf16x3).
// Per step: cached A burst -> MFMA -> 2-phase LDS reduce -> per-thread epilogue
// (each thread owns one (row,col), h_old in register) -> write-through h store
// -> global barrier -> agent acquire fence (L1/L2 inv).
__global__ void __launch_bounds__(512, 1)
esn_scan(const float* __restrict__ inp, const float* __restrict__ alpha,
         const ushort* __restrict__ Wth, const ushort* __restrict__ Wtl,
         ushort* __restrict__ a0, ushort* __restrict__ a1,
         float* __restrict__ out, unsigned* __restrict__ bar) {
  extern __shared__ ushort smem[];
  float* red = (float*)(smem + REDOFF);   // 8 tiles x 64 lanes x f32x4 = 8 KB

  const int bid = blockIdx.x;
  const int pb = bid & 1, cb = bid >> 1;  // cb in [0,125)
  const int tid = threadIdx.x;
  const int ks = tid >> 6, lane = tid & 63;
  const int l15 = lane & 15, lk = lane >> 4;

  // ---- one-time: stage W col-slice (hi+lo) into LDS ----
  {
    const uint4* srcH = (const uint4*)(Wth + (size_t)cb * 16 * KPAD);
    const uint4* srcL = (const uint4*)(Wtl + (size_t)cb * 16 * KPAD);
    uint4* dstH = (uint4*)smem;
    uint4* dstL = (uint4*)(smem + 16*WLSTR);
    for (int idx = tid; idx < 16*(KPAD/8); idx += 512) {
      const int c = idx / (KPAD/8), j = idx - c*(KPAD/8);
      dstH[c*(WLSTR/8) + j] = srcH[idx];
      dstL[c*(WLSTR/8) + j] = srcL[idx];
    }
  }
  __syncthreads();

  const ushort* pBh = smem + l15*WLSTR + lk*8 + ks*9*32;
  const ushort* pBl = pBh + 16*WLSTR;

  // A-load byte voffsets (saddr = swapped buffer base)
  const unsigned voffA0 = 2u*((unsigned)((pb*2+0)*MT_STRIDE + ks*9*1024) + (unsigned)lane*8u);
  const unsigned voffA1 = voffA0 + 2u*MT_STRIDE;

  // ---- per-thread epilogue mapping: thread owns (row32 = tid>>4, ec = tid&15) ----
  const int row32 = tid >> 4;            // 0..31 (local batch row)
  const int ec    = tid & 15;            // 0..15 (local col)
  const int mi3   = row32 >> 4;          // which 16-row mtile
  const int r16   = row32 & 15;
  const int lanep = (r16 >> 2)*16 + ec;  // lane holding (r16,ec) in a D tile
  const int ereg  = r16 & 3;
  const int col   = cb*16 + ec;          // global col, always < 2000
  const float av  = alpha[col];
  const unsigned voffE = 2u*(unsigned)((pb*2+mi3)*MT_STRIDE + (col>>5)*1024
                       + ((col>>3)&3)*128 + r16*8 + (col&7));
  float hold = 0.f;                      // h carried per-thread in fp32

  // u-staging mapping (waves 4..7 of blocks cb<32): one batch row, 256 floats
  const int t2 = tid - 256;
  const int sb = pb*32 + cb;
  unsigned voffS = 0; const float* inpS = inp;
  if (tid >= 256 && cb < 32) {
    const int kS = UNITS + t2;
    voffS = 2u*((unsigned)((sb>>4)*MT_STRIDE) + (unsigned)((kS>>5)*1024
          + ((kS>>3)&3)*128 + (sb&15)*8 + (kS&7)));
    inpS = inp + (size_t)sb * TSTEPS * FDIM + t2;
  }

  const ushort* Acur = a0;
  ushort* Anxt = a1;

  const unsigned gi = (unsigned)(bid & 15);
  const unsigned leafsz = (gi < 10) ? 16u : 15u;
  unsigned* leafp = bar + gi*32;
  unsigned* rootp = bar + 520;
  unsigned* genp  = bar + 528;
  unsigned* ggenp = bar + 544 + gi*32;

  for (int t = 0; t < TSTEPS; ++t) {
    // ---- cached A burst: 36 x 16 B per wave, fully coalesced ----
    short8 fh0[9], fl0[9], fh1[9], fl1[9];
    #pragma unroll
    for (int j = 0; j < 9; ++j) {
      const unsigned vo0 = voffA0 + (unsigned)j*2048u;
      const unsigned vo1 = voffA1 + (unsigned)j*2048u;
      fh0[j] = load_cached<0>(vo0, Acur);
      fl0[j] = load_cached<1024>(vo0, Acur);
      fh1[j] = load_cached<0>(vo1, Acur);
      fl1[j] = load_cached<1024>(vo1, Acur);
    }

    f32x4 acc[2][3];
    #pragma unroll
    for (int a = 0; a < 2; ++a)
      #pragma unroll
      for (int b = 0; b < 3; ++b) acc[a][b] = (f32x4){0.f,0.f,0.f,0.f};

#define COMPUTE(j) { \
      const short8 bh = *(const short8*)(pBh + (j)*32); \
      const short8 bl = *(const short8*)(pBl + (j)*32); \
      acc[0][0] = __builtin_amdgcn_mfma_f32_16x16x32_bf16(fh0[j], bh, acc[0][0], 0,0,0); \
      acc[0][1] = __builtin_amdgcn_mfma_f32_16x16x32_bf16(fh0[j], bl, acc[0][1], 0,0,0); \
      acc[0][2] = __builtin_amdgcn_mfma_f32_16x16x32_bf16(fl0[j], bh, acc[0][2], 0,0,0); \
      acc[1][0] = __builtin_amdgcn_mfma_f32_16x16x32_bf16(fh1[j], bh, acc[1][0], 0,0,0); \
      acc[1][1] = __builtin_amdgcn_mfma_f32_16x16x32_bf16(fh1[j], bl, acc[1][1], 0,0,0); \
      acc[1][2] = __builtin_amdgcn_mfma_f32_16x16x32_bf16(fl1[j], bh, acc[1][2], 0,0,0); }

    asm volatile("s_waitcnt vmcnt(16)" ::: "memory");   // first 5 ki (20 loads) done
    __builtin_amdgcn_sched_barrier(0);
    #pragma unroll
    for (int j = 0; j < 5; ++j) COMPUTE(j)
    asm volatile("s_waitcnt vmcnt(0)" ::: "memory");
    __builtin_amdgcn_sched_barrier(0);
    #pragma unroll
    for (int j = 5; j < 9; ++j) COMPUTE(j)
#undef COMPUTE

    f32x4 s0 = acc[0][0] + acc[0][1] + acc[0][2];
    f32x4 s1 = acc[1][0] + acc[1][1] + acc[1][2];

    // ---- phase 1: waves 4..7 publish partials ----
    if (ks >= 4) {
      *(f32x4*)(red + (((ks-4)*2+0)*64 + lane)*4) = s0;
      *(f32x4*)(red + (((ks-4)*2+1)*64 + lane)*4) = s1;
    }
    __syncthreads();
    // ---- phase 2: waves 0..3 combine pairwise; waves 4..7 stage u_{t+1} ----
    if (ks < 4) {
      s0 += *(const f32x4*)(red + ((ks*2+0)*64 + lane)*4);
      s1 += *(const f32x4*)(red + ((ks*2+1)*64 + lane)*4);
      *(f32x4*)(red + ((ks*2+0)*64 + lane)*4) = s0;
      *(f32x4*)(red + ((ks*2+1)*64 + lane)*4) = s1;
    } else if (tid >= 256 && cb < 32 && t+1 < TSTEPS) {
      const float u = inpS[(size_t)(t+1)*FDIM];
      const ushort hi = f2bf(u);
      store_coh<0>(voffS, Anxt, hi);
      store_coh<1024>(voffS, Anxt, f2bf(u - bf2f(hi)));
    }
    __syncthreads();

    // ---- phase 3: all 512 threads, one (row,col) each ----
    {
      float s = 0.f;
      #pragma unroll
      for (int q = 0; q < 4; ++q)
        s += red[((q*2+mi3)*64 + lanep)*4 + ereg];
      const float hn = (1.f - av) * hold + av * tanhf(s);
      hold = hn;
      const ushort hi = f2bf(hn);
      store_coh<0>(voffE, Anxt, hi);
      store_coh<1024>(voffE, Anxt, f2bf(hn - bf2f(hi)));
      if (t == TSTEPS-1) out[(size_t)(pb*32 + row32)*UNITS + col] = hn;
    }

    asm volatile("s_waitcnt vmcnt(0)" ::: "memory");  // h stores at coherence point
    __syncthreads();

    if (t + 1 < TSTEPS) {
      if (tid == 0) {
        const unsigned tgt = (unsigned)(t+1);
        const unsigned old = __hip_atomic_fetch_add(leafp, 1u, __ATOMIC_RELAXED,
                                                    __HIP_MEMORY_SCOPE_AGENT);
        if (old == tgt*leafsz - 1u) {
          const unsigned o2 = __hip_atomic_fetch_add(rootp, 1u, __ATOMIC_RELAXED,
                                                     __HIP_MEMORY_SCOPE_AGENT);
          if (o2 == tgt*16u - 1u)
            __hip_atomic_store(genp, tgt, __ATOMIC_RELAXED, __HIP_MEMORY_SCOPE_AGENT);
          while (__hip_atomic_load(genp, __ATOMIC_RELAXED, __HIP_MEMORY_SCOPE_AGENT) < tgt)
            __builtin_amdgcn_s_sleep(1);
          __hip_atomic_store(ggenp, tgt, __ATOMIC_RELAXED, __HIP_MEMORY_SCOPE_AGENT);
        } else {
          while (__hip_atomic_load(ggenp, __ATOMIC_RELAXED, __HIP_MEMORY_SCOPE_AGENT) < tgt)
            __builtin_amdgcn_s_sleep(1);
        }
        // invalidate this CU's L1 + this XCD's L2 so cached A-loads see fresh L3
        __builtin_amdgcn_fence(__ATOMIC_ACQUIRE, "agent");
      }
      __syncthreads();
    }
    const ushort* tmp = Acur; Acur = Anxt; Anxt = (ushort*)tmp;
  }
}

// ---------------- launch ----------------
extern "C" void kernel_launch(void* const* d_in, const int* in_sizes, int n_in,
                              void* d_out, int out_size, void* d_ws, size_t ws_size,
                              hipStream_t stream) {
  const float* inp   = (const float*)d_in[0];   // (64,1024,256)
  const float* W_in  = (const float*)d_in[1];   // (256,2000)
  const float* W_res = (const float*)d_in[2];   // (2000,2000)
  const float* alpha = (const float*)d_in[3];   // (1,2000)
  float* out = (float*)d_out;                   // (64,2000)

  ushort* Wth = (ushort*)d_ws;
  ushort* Wtl = Wth + WELEMS;
  ushort* a0  = Wtl + WELEMS;
  ushort* a1  = a0 + ABUF_USH;
  unsigned* bar = (unsigned*)(a1 + ABUF_USH);   // 2048 uints

  (void)hipFuncSetAttribute((const void*)esn_scan,
                            hipFuncAttributeMaxDynamicSharedMemorySize, SMEM_BYTES);

  hipLaunchKernelGGL(prep_w, dim3(KPAD/32, NPAD/32), dim3(32, 8), 0, stream,
                     W_in, W_res, Wth, Wtl);
  hipLaunchKernelGGL(init_abuf, dim3((ABUF_USH + 255) / 256), dim3(256), 0, stream,
                     inp, a0, a1, bar);
  hipLaunchKernelGGL(esn_scan, dim3(NBLK), dim3(512), SMEM_BYTES, stream,
                     inp, alpha, Wth, Wtl, a0, a1, out, bar);
}

// Round 5
// 4665.389 us; speedup vs baseline: 1.7777x; 1.7777x over previous
//
#include <hip/hip_runtime.h>
#include <hip/hip_bf16.h>

// ---------------- problem constants ----------------
#define UNITS    2000
#define FDIM     256
#define TSTEPS   1024
#define BATCH    64
#define KPAD     2304                 // 2000 h + 256 u + 48 pad = 32*72
#define NPAD     2048
#define WLSTR    2312                 // LDS W row stride (ushorts): 2-way bank alias only
#define MT_STRIDE 73728               // ushorts per 16-row mtile = 72 ki * 1024
#define ABUF_USH 294912               // 4 mtiles (per buffer)
#define WELEMS   ((size_t)NPAD * KPAD)
#define NCG      63                   // col-groups of 32 (cols 2000..2015 dead)
#define NBLK     252                  // 4 row-groups x 63 col-groups
#define REDOFF   (32*WLSTR)           // ushort offset of reduction scratch
#define SMEM_BYTES (REDOFF*2 + 8192)  // 147,968 + 8,192 = 156,160 B

typedef __attribute__((ext_vector_type(8))) short short8;   // 8 bf16
typedef __attribute__((ext_vector_type(4))) float f32x4;

static __device__ __forceinline__ ushort f2bf(float x) {
  union { float f; unsigned u; } v; v.f = x;
  unsigned r = v.u + 0x7fff + ((v.u >> 16) & 1);
  return (ushort)(r >> 16);
}
static __device__ __forceinline__ float bf2f(ushort h) {
  union { float f; unsigned u; } v; v.u = ((unsigned)h) << 16;
  return v.f;
}

// Coherent (L1/L2-bypassing, Infinity-Cache-backed) 16-B load / 2-B store.
// r3-validated path: stores write through to L3 (the coherence point), loads
// read L3 directly -> no per-step cache maintenance needed.
template<int OFF>
static __device__ __forceinline__ short8 load_coh(unsigned voff, const ushort* base) {
  short8 r;
  asm volatile("global_load_dwordx4 %0, %1, %2 offset:%3 sc0 sc1"
               : "=v"(r) : "v"(voff), "s"(base), "n"(OFF));
  return r;
}
template<int OFF>
static __device__ __forceinline__ void store_coh(unsigned voff, ushort* base, ushort val) {
  const unsigned v32 = val;
  asm volatile("global_store_short %0, %1, %2 offset:%3 sc0 sc1"
               :: "v"(voff), "v"(v32), "s"(base), "n"(OFF) : "memory");
}

// ---------------- W prep: transpose + bf16 hi/lo split (validated r1-r4) ----
__global__ void prep_w(const float* __restrict__ W_in, const float* __restrict__ W_res,
                       ushort* __restrict__ Wth, ushort* __restrict__ Wtl) {
  __shared__ float tile[32][33];
  const int tk = blockIdx.x, tn = blockIdx.y;
  const int tx = threadIdx.x, ty = threadIdx.y;
  const int n = tn * 32 + tx;
  #pragma unroll
  for (int i = 0; i < 32; i += 8) {
    const int k = tk * 32 + ty + i;
    float v = 0.f;
    if (n < UNITS) {
      if (k < UNITS)            v = W_res[(size_t)k * UNITS + n];
      else if (k < UNITS+FDIM)  v = W_in[(size_t)(k - UNITS) * UNITS + n];
    }
    tile[ty + i][tx] = v;
  }
  __syncthreads();
  #pragma unroll
  for (int i = 0; i < 32; i += 8) {
    const int row = tn * 32 + ty + i;
    const int kk  = tk * 32 + tx;
    const float v = tile[tx][ty + i];
    const ushort hi = f2bf(v);
    const ushort lo = f2bf(v - bf2f(hi));
    Wth[(size_t)row * KPAD + kk] = hi;
    Wtl[(size_t)row * KPAD + kk] = lo;
  }
}

// ---------------- A-buffer (fragment layout) + barrier init ----------------
// ushort offset F(row,k,part) = (row>>4)*MT_STRIDE + (k>>5)*1024 + part*512
//                              + ((k>>3)&3)*128 + (row&15)*8 + (k&7)
__global__ void init_abuf(const float* __restrict__ inp,
                          ushort* __restrict__ a0, ushort* __restrict__ a1,
                          unsigned* __restrict__ bar) {
  const int i = blockIdx.x * 256 + threadIdx.x;
  if (i < 2048) bar[i] = 0u;
  if (i >= ABUF_USH) return;
  const int mtile = i / MT_STRIDE;
  const int r1 = i - mtile * MT_STRIDE;
  const int ki  = r1 >> 10;
  const int rem = r1 & 1023;
  const int part = rem >> 9;
  const int lk  = (rem >> 7) & 3;
  const int l15 = (rem >> 3) & 15;
  const int el  = rem & 7;
  const int row = mtile * 16 + l15;
  const int k   = ki * 32 + lk * 8 + el;
  ushort v = 0;
  if (k >= UNITS && k < UNITS + FDIM) {
    const float u = inp[(size_t)row * TSTEPS * FDIM + (k - UNITS)];   // t = 0
    const ushort hi = f2bf(u);
    v = part ? f2bf(u - bf2f(hi)) : hi;
  }
  a0[i] = v; a1[i] = 0;
}

// ---------------- the scan ----------------
// 252 blocks x 512 thr (8 waves), 1 block/CU. Block (rg,cg): rows [rg*16,+16),
// cols [cg*32,+32). W-hi (32 cols) in LDS; W-lo in registers (72 VGPR/wave).
// Wave ks owns K-eighth x 1 M-tile x 2 N-tiles (bf16x3: ah*bh + ah*wlo + al*bh).
// Block reads ONLY its row-group's h -> 4 independent 63-block barriers.
__global__ void __launch_bounds__(512, 2)
esn_scan(const float* __restrict__ inp, const float* __restrict__ alpha,
         const ushort* __restrict__ Wth, const ushort* __restrict__ Wtl,
         ushort* __restrict__ a0, ushort* __restrict__ a1,
         float* __restrict__ out, unsigned* __restrict__ bar) {
  extern __shared__ ushort smem[];
  float* red = (float*)(smem + REDOFF);   // 8 tiles x 64 lanes x f32x4 = 8 KB

  const int bid = blockIdx.x;
  const int rg  = bid / NCG;              // 0..3  (row-group)
  const int cg  = bid - rg * NCG;         // 0..62 (col-group)
  const int tid = threadIdx.x;
  const int ks = tid >> 6, lane = tid & 63;
  const int l15 = lane & 15, lk = lane >> 4;

  // ---- one-time: stage W-hi col-slice (32 cols) into LDS ----
  {
    const uint4* srcH = (const uint4*)(Wth + (size_t)cg * 32 * KPAD);
    uint4* dstH = (uint4*)smem;
    for (int idx = tid; idx < 32*(KPAD/8); idx += 512) {
      const int c = idx / (KPAD/8), j = idx - c*(KPAD/8);
      dstH[c*(WLSTR/8) + j] = srcH[idx];
    }
  }
  // ---- one-time: W-lo fragments into registers (9 ki x 2 ntiles) ----
  short8 wlo[9][2];
  #pragma unroll
  for (int ki = 0; ki < 9; ++ki)
    #pragma unroll
    for (int nt = 0; nt < 2; ++nt)
      wlo[ki][nt] = *(const short8*)(Wtl + (size_t)(cg*32 + nt*16 + l15) * KPAD
                                        + ks*288 + ki*32 + lk*8);
  __syncthreads();

  const ushort* pBh0 = smem + (0*16 + l15)*WLSTR + lk*8 + ks*288;
  const ushort* pBh1 = smem + (1*16 + l15)*WLSTR + lk*8 + ks*288;

  // A-load byte voffset (only this block's 16-row mtile)
  const unsigned voffA = 2u*((unsigned)(rg*MT_STRIDE + ks*9216) + (unsigned)lane*8u);

  // ---- per-thread epilogue mapping: thread owns (r = tid>>5, c = tid&31) ----
  const int r    = tid >> 5;             // 0..15 local row
  const int c    = tid & 31;             // 0..31 local col
  const int nt3  = c >> 4;               // which 16-col ntile
  const int cl   = c & 15;
  const int lanep = (r >> 2)*16 + cl;    // lane holding (r,cl) in a D tile
  const int ereg  = r & 3;
  const int col   = cg*32 + c;           // global col (may be >= 2000: dead)
  const int grow  = rg*16 + r;           // global row
  const float av  = (col < UNITS) ? alpha[col] : 0.f;
  const unsigned voffE = 2u*(unsigned)(rg*MT_STRIDE + (col>>5)*1024
                       + ((col>>3)&3)*128 + r*8 + (col&7));
  float hold = 0.f;                      // h carried per-thread in fp32

  // u-staging mapping (waves 4..7 of blocks cg<16): row rg*16+cg, 256 floats
  const int t2 = tid - 256;
  const int sb = rg*16 + cg;
  unsigned voffS = 0; const float* inpS = inp;
  if (tid >= 256 && cg < 16) {
    const int kS = UNITS + t2;
    voffS = 2u*((unsigned)(rg*MT_STRIDE) + (unsigned)((kS>>5)*1024
          + ((kS>>3)&3)*128 + (sb&15)*8 + (kS&7)));
    inpS = inp + (size_t)sb * TSTEPS * FDIM + t2;
  }

  const ushort* Acur = a0;
  ushort* Anxt = a1;

  unsigned* cnt = bar + rg*32;           // per-row-group monotone counter
  unsigned* gen = bar + 256 + rg*32;     // per-row-group generation

  for (int t = 0; t < TSTEPS; ++t) {
    // ---- coherent A burst: 18 x 16 B per wave, fully coalesced ----
    short8 fh[9], fl[9];
    #pragma unroll
    for (int j = 0; j < 9; ++j) {
      const unsigned vo = voffA + (unsigned)j*2048u;
      fh[j] = load_coh<0>(vo, Acur);
      fl[j] = load_coh<1024>(vo, Acur);
    }

    f32x4 acc[2][3];
    #pragma unroll
    for (int a = 0; a < 2; ++a)
      #pragma unroll
      for (int b = 0; b < 3; ++b) acc[a][b] = (f32x4){0.f,0.f,0.f,0.f};

#define COMPUTE(j) { \
      const short8 bh0 = *(const short8*)(pBh0 + (j)*32); \
      const short8 bh1 = *(const short8*)(pBh1 + (j)*32); \
      acc[0][0] = __builtin_amdgcn_mfma_f32_16x16x32_bf16(fh[j], bh0, acc[0][0], 0,0,0); \
      acc[0][1] = __builtin_amdgcn_mfma_f32_16x16x32_bf16(fh[j], wlo[j][0], acc[0][1], 0,0,0); \
      acc[0][2] = __builtin_amdgcn_mfma_f32_16x16x32_bf16(fl[j], bh0, acc[0][2], 0,0,0); \
      acc[1][0] = __builtin_amdgcn_mfma_f32_16x16x32_bf16(fh[j], bh1, acc[1][0], 0,0,0); \
      acc[1][1] = __builtin_amdgcn_mfma_f32_16x16x32_bf16(fh[j], wlo[j][1], acc[1][1], 0,0,0); \
      acc[1][2] = __builtin_amdgcn_mfma_f32_16x16x32_bf16(fl[j], bh1, acc[1][2], 0,0,0); }

    asm volatile("s_waitcnt vmcnt(8)" ::: "memory");   // first 5 ki (10 loads) done
    __builtin_amdgcn_sched_barrier(0);
    #pragma unroll
    for (int j = 0; j < 5; ++j) COMPUTE(j)
    asm volatile("s_waitcnt vmcnt(0)" ::: "memory");
    __builtin_amdgcn_sched_barrier(0);
    #pragma unroll
    for (int j = 5; j < 9; ++j) COMPUTE(j)
#undef COMPUTE

    f32x4 s0 = acc[0][0] + acc[0][1] + acc[0][2];
    f32x4 s1 = acc[1][0] + acc[1][1] + acc[1][2];

    // ---- phase 1: waves 4..7 publish partials ----
    if (ks >= 4) {
      *(f32x4*)(red + (((ks-4)*2+0)*64 + lane)*4) = s0;
      *(f32x4*)(red + (((ks-4)*2+1)*64 + lane)*4) = s1;
    }
    __syncthreads();
    // ---- phase 2: waves 0..3 combine pairwise; waves 4..7 stage u_{t+1} ----
    if (ks < 4) {
      s0 += *(const f32x4*)(red + ((ks*2+0)*64 + lane)*4);
      s1 += *(const f32x4*)(red + ((ks*2+1)*64 + lane)*4);
      *(f32x4*)(red + ((ks*2+0)*64 + lane)*4) = s0;
      *(f32x4*)(red + ((ks*2+1)*64 + lane)*4) = s1;
    } else if (tid >= 256 && cg < 16 && t+1 < TSTEPS) {
      const float u = inpS[(size_t)(t+1)*FDIM];
      const ushort hi = f2bf(u);
      store_coh<0>(voffS, Anxt, hi);
      store_coh<1024>(voffS, Anxt, f2bf(u - bf2f(hi)));
    }
    __syncthreads();

    // ---- phase 3: all 512 threads, one (row,col) each ----
    if (col < UNITS) {
      float s = 0.f;
      #pragma unroll
      for (int q = 0; q < 4; ++q)
        s += red[((q*2+nt3)*64 + lanep)*4 + ereg];
      const float hn = (1.f - av) * hold + av * tanhf(s);
      hold = hn;
      const ushort hi = f2bf(hn);
      store_coh<0>(voffE, Anxt, hi);
      store_coh<1024>(voffE, Anxt, f2bf(hn - bf2f(hi)));
      if (t == TSTEPS-1) out[(size_t)grow*UNITS + col] = hn;
    }

    asm volatile("s_waitcnt vmcnt(0)" ::: "memory");  // per-wave: h stores at L3
    __syncthreads();

    if (t + 1 < TSTEPS) {
      if (tid == 0) {
        const unsigned tgt = (unsigned)(t+1);
        const unsigned old = __hip_atomic_fetch_add(cnt, 1u, __ATOMIC_RELAXED,
                                                    __HIP_MEMORY_SCOPE_AGENT);
        if (old == tgt*(unsigned)NCG - 1u) {
          __hip_atomic_store(gen, tgt, __ATOMIC_RELAXED, __HIP_MEMORY_SCOPE_AGENT);
        } else {
          while (__hip_atomic_load(gen, __ATOMIC_RELAXED, __HIP_MEMORY_SCOPE_AGENT) < tgt)
            __builtin_amdgcn_s_sleep(1);
        }
      }
      __syncthreads();
    }
    const ushort* tmp = Acur; Acur = Anxt; Anxt = (ushort*)tmp;
  }
}

// ---------------- launch ----------------
extern "C" void kernel_launch(void* const* d_in, const int* in_sizes, int n_in,
                              void* d_out, int out_size, void* d_ws, size_t ws_size,
                              hipStream_t stream) {
  const float* inp   = (const float*)d_in[0];   // (64,1024,256)
  const float* W_in  = (const float*)d_in[1];   // (256,2000)
  const float* W_res = (const float*)d_in[2];   // (2000,2000)
  const float* alpha = (const float*)d_in[3];   // (1,2000)
  float* out = (float*)d_out;                   // (64,2000)

  ushort* Wth = (ushort*)d_ws;
  ushort* Wtl = Wth + WELEMS;
  ushort* a0  = Wtl + WELEMS;
  ushort* a1  = a0 + ABUF_USH;
  unsigned* bar = (unsigned*)(a1 + ABUF_USH);   // 2048 uints

  (void)hipFuncSetAttribute((const void*)esn_scan,
                            hipFuncAttributeMaxDynamicSharedMemorySize, SMEM_BYTES);

  hipLaunchKernelGGL(prep_w, dim3(KPAD/32, NPAD/32), dim3(32, 8), 0, stream,
                     W_in, W_res, Wth, Wtl);
  hipLaunchKernelGGL(init_abuf, dim3((ABUF_USH + 255) / 256), dim3(256), 0, stream,
                     inp, a0, a1, bar);
  hipLaunchKernelGGL(esn_scan, dim3(NBLK), dim3(512), SMEM_BYTES, stream,
                     inp, alpha, Wth, Wtl, a0, a1, out, bar);
}